// Round 5
// baseline (419.040 us; speedup 1.0000x reference)
//
#include <hip/hip_runtime.h>
#include <hip/hip_bf16.h>

#define BATCH 128
#define LQ    512
#define LK    512
#define DH    64
#define TQ    16
#define KC    128     // phase-1 K column-chunk
#define VC    64      // phase-3 V k-chunk per stage

// scs: fp16 scores then bf16 attn overlay. SSTR=520 (1040 B rows): phase-2
// b64 r/w and phase-3 b128 A-frag reads bank-balanced (round-2/4 audit).
#define SSTR  520

// vt: per-wave private 16d x VC(64)k bf16, row stride 64 shorts = exactly
// 32 banks, XOR swizzle group g^(d&15). Audited: stores 4 dwords/bank
// balanced, reads 4 dwords/bank balanced -> zero conflict cycles. Wave-
// private => phase 3 needs NO __syncthreads at all.

typedef float    float4v __attribute__((ext_vector_type(4)));
typedef short    short8v __attribute__((ext_vector_type(8)));
typedef short    short4v __attribute__((ext_vector_type(4)));
typedef int      int4v   __attribute__((ext_vector_type(4)));
typedef _Float16 half4v  __attribute__((ext_vector_type(4)));

__device__ __forceinline__ short bf16r(float f) {
  union { float f; unsigned u; } x; x.f = f;
  unsigned r = x.u + 0x7FFFu + ((x.u >> 16) & 1u);
  return (short)(r >> 16);
}

// packed fp32x2 -> bf16x2 (gfx950 v_cvt_pk_bf16_f32 when available)
__device__ __forceinline__ unsigned pkbf16(float a, float b) {
#if __has_builtin(__builtin_amdgcn_cvt_pk_bf16_f32)
  auto r = __builtin_amdgcn_cvt_pk_bf16_f32(a, b);
  unsigned i; __builtin_memcpy(&i, &r, 4); return i;
#else
  return ((unsigned)(unsigned short)bf16r(a)) |
         ((unsigned)(unsigned short)bf16r(b) << 16);
#endif
}

__device__ __forceinline__ int4v ntload4(const int* p) {
  return __builtin_nontemporal_load((const int4v*)p);
}

__global__ __launch_bounds__(256, 6)
void sdpa_kernel(const float* __restrict__ Q, const float* __restrict__ K,
                 const float* __restrict__ V, const int* __restrict__ KM,
                 const int* __restrict__ QM, float* __restrict__ OUT,
                 float* __restrict__ ATT)
{
  __shared__ short scs[TQ * SSTR];     // 16640 B
  __shared__ short vt[4 * 16 * VC];    //  8192 B -> 24.8 KB total, 6 blocks/CU

  const int b    = blockIdx.x >> 5;
  const int q0   = (blockIdx.x & 31) * TQ;
  const int tid  = threadIdx.x;
  const int lane = tid & 63;
  const int wave = tid >> 6;
  const int lm   = lane & 15;
  const int quad = lane >> 4;

  const int row = tid >> 4;
  const int col = tid & 15;
  const size_t gro = (size_t)(b * LQ + q0 + row) * LK;

  // Key-mask prefetch: ~900-cyc HBM latency hides behind all of phase 1.
  int4v kmv[8];
#pragma unroll
  for (int j = 0; j < 8; ++j)
    kmv[j] = ntload4(KM + gro + col * 4 + j * 64);

  // ---------------- Q A-fragments in registers ---------------------------
  const float* qrow = Q + ((size_t)(b * LQ + q0 + lm)) * DH + quad * 8;
  short8v aq0, aq1;
  {
    float4v f0 = __builtin_nontemporal_load((const float4v*)(qrow + 0));
    float4v f1 = __builtin_nontemporal_load((const float4v*)(qrow + 4));
    float4v f2 = __builtin_nontemporal_load((const float4v*)(qrow + 32));
    float4v f3 = __builtin_nontemporal_load((const float4v*)(qrow + 36));
    unsigned* a0 = (unsigned*)&aq0;
    unsigned* a1 = (unsigned*)&aq1;
    a0[0] = pkbf16(f0[0], f0[1]); a0[1] = pkbf16(f0[2], f0[3]);
    a0[2] = pkbf16(f1[0], f1[1]); a0[3] = pkbf16(f1[2], f1[3]);
    a1[0] = pkbf16(f2[0], f2[1]); a1[1] = pkbf16(f2[2], f2[3]);
    a1[2] = pkbf16(f3[0], f3[1]); a1[3] = pkbf16(f3[2], f3[3]);
  }

  // ---------------- Phase 1: S = Q K^T, K direct from L2 -----------------
  // 1-deep software pipeline over 8 (kt,t) tiles; no barriers inside.
  {
    float4v c0, c1, c2, c3;
    {
      const float* kr = K + ((size_t)(b * LK + (wave * 2) * 16 + lm)) * DH + quad * 8;
      c0 = *(const float4v*)(kr + 0);  c1 = *(const float4v*)(kr + 4);
      c2 = *(const float4v*)(kr + 32); c3 = *(const float4v*)(kr + 36);
    }
#pragma unroll
    for (int p = 0; p < 8; ++p) {
      float4v n0, n1, n2, n3;
      if (p < 7) {
        int np = p + 1, kt = np >> 1, t = np & 1;
        const float* kr = K + ((size_t)(b * LK + kt * KC + (wave * 2 + t) * 16 + lm)) * DH + quad * 8;
        n0 = *(const float4v*)(kr + 0);  n1 = *(const float4v*)(kr + 4);
        n2 = *(const float4v*)(kr + 32); n3 = *(const float4v*)(kr + 36);
      }
      short8v b0, b1;
      {
        unsigned* p0 = (unsigned*)&b0;
        unsigned* p1 = (unsigned*)&b1;
        p0[0] = pkbf16(c0[0], c0[1]); p0[1] = pkbf16(c0[2], c0[3]);
        p0[2] = pkbf16(c1[0], c1[1]); p0[3] = pkbf16(c1[2], c1[3]);
        p1[0] = pkbf16(c2[0], c2[1]); p1[1] = pkbf16(c2[2], c2[3]);
        p1[2] = pkbf16(c3[0], c3[1]); p1[3] = pkbf16(c3[2], c3[3]);
      }
      float4v acc = {0.f, 0.f, 0.f, 0.f};
      acc = __builtin_amdgcn_mfma_f32_16x16x32_bf16(aq0, b0, acc, 0, 0, 0);
      acc = __builtin_amdgcn_mfma_f32_16x16x32_bf16(aq1, b1, acc, 0, 0, 0);
      int kt = p >> 1, t = p & 1;
      int n  = kt * KC + (wave * 2 + t) * 16 + lm;
      int m0 = quad * 4;
#pragma unroll
      for (int j = 0; j < 4; ++j)
        *(_Float16*)&scs[(m0 + j) * SSTR + n] = (_Float16)acc[j];
      if (p < 7) { c0 = n0; c1 = n1; c2 = n2; c3 = n3; }
    }
  }
  __syncthreads();                       // barrier 1 of 2: scores ready

  // ---------------- Phase 2: masks + softmax -----------------------------
  float s[32];
  float mx = -INFINITY;
#pragma unroll
  for (int j = 0; j < 8; ++j) {
    half4v h4 = *(const half4v*)&scs[row * SSTR + col * 4 + j * 64];
#pragma unroll
    for (int e = 0; e < 4; ++e) {
      float val = kmv[j][e] ? -INFINITY : (float)h4[e];
      s[j * 4 + e] = val;
      mx = fmaxf(mx, val);
    }
  }
  // query-mask loads issued early: latency overlaps shuffles + exp
  int4v qmv[8];
#pragma unroll
  for (int j = 0; j < 8; ++j)
    qmv[j] = ntload4(QM + gro + col * 4 + j * 64);
#pragma unroll
  for (int off = 8; off; off >>= 1) mx = fmaxf(mx, __shfl_xor(mx, off, 64));
  float sum = 0.f;
#pragma unroll
  for (int j = 0; j < 32; ++j) {
    float p = __expf((s[j] - mx) * 0.125f);
    s[j] = p;
    sum += p;
  }
#pragma unroll
  for (int off = 8; off; off >>= 1) sum += __shfl_xor(sum, off, 64);
  const float inv = 1.f / sum;
  float* arow = ATT + gro;
#pragma unroll
  for (int j = 0; j < 8; ++j) {
    int kk = col * 4 + j * 64;
    float4v a4;
#pragma unroll
    for (int e = 0; e < 4; ++e)
      a4[e] = qmv[j][e] ? 0.f : s[j * 4 + e] * inv;
    __builtin_nontemporal_store(a4, (float4v*)(arow + kk));  // fp32 attn out
    short4v ab;
    unsigned* abp = (unsigned*)&ab;
    abp[0] = pkbf16(a4[0], a4[1]);
    abp[1] = pkbf16(a4[2], a4[3]);
    *(short4v*)&scs[row * SSTR + kk] = ab;     // in-place bf16 overlay
  }

  // ---------------- Phase 3: O = A V, wave-private Vt, NO barriers -------
  // Lane roles: Bk = k-block (4 k's), dblk = quad -> d' = quad*4+e.
  const int Bk = lm;
  short* vtw = vt + wave * (16 * VC);

  // stage chunk 0 loads before the attn barrier: latency overlaps it
  float4v vr[4];
  {
    const float* vp = V + ((size_t)(b * LK + Bk * 4)) * DH + wave * 16 + quad * 4;
#pragma unroll
    for (int r = 0; r < 4; ++r) vr[r] = *(const float4v*)(vp + r * DH);
  }
  __syncthreads();                       // barrier 2 of 2: attn ready

  float4v oacc = {0.f, 0.f, 0.f, 0.f};
#pragma unroll
  for (int c = 0; c < 8; ++c) {
    float4v vn[4];
    if (c < 7) {
      const float* vp = V + ((size_t)(b * LK + (c + 1) * VC + Bk * 4)) * DH + wave * 16 + quad * 4;
#pragma unroll
      for (int r = 0; r < 4; ++r) vn[r] = *(const float4v*)(vp + r * DH);
    }
    // store chunk c into wave-private vt (XOR swizzle, conflict-free)
#pragma unroll
    for (int e = 0; e < 4; ++e) {
      int dp = quad * 4 + e;
      int gp = Bk ^ dp;
      short4v s4;
      unsigned* sp = (unsigned*)&s4;
      sp[0] = pkbf16(vr[0][e], vr[1][e]);
      sp[1] = pkbf16(vr[2][e], vr[3][e]);
      *(short4v*)&vtw[dp * VC + gp * 4] = s4;
    }
    // consume: 2 MFMAs (k = c*64 .. c*64+63); same-wave lgkmcnt orders LDS
#pragma unroll
    for (int ks = 0; ks < 2; ++ks) {
      const short* ap = &scs[lm * SSTR + c * VC + ks * 32 + quad * 8];
      short8v a8 = *(const short8v*)ap;
      int g0 = ks * 8 + quad * 2;
      short4v lo = *(const short4v*)&vtw[lm * VC + ((g0    ) ^ lm) * 4];
      short4v hi = *(const short4v*)&vtw[lm * VC + ((g0 + 1) ^ lm) * 4];
      short8v b8;
      b8[0] = lo[0]; b8[1] = lo[1]; b8[2] = lo[2]; b8[3] = lo[3];
      b8[4] = hi[0]; b8[5] = hi[1]; b8[6] = hi[2]; b8[7] = hi[3];
      oacc = __builtin_amdgcn_mfma_f32_16x16x32_bf16(a8, b8, oacc, 0, 0, 0);
    }
    if (c < 7) {
#pragma unroll
      for (int r = 0; r < 4; ++r) vr[r] = vn[r];
    }
  }
  {
    int m0 = quad * 4;
    float* obase = OUT + ((size_t)(b * LQ + q0 + m0)) * DH + wave * 16 + lm;
#pragma unroll
    for (int j = 0; j < 4; ++j)
      __builtin_nontemporal_store(oacc[j], obase + j * DH);
  }
}

extern "C" void kernel_launch(void* const* d_in, const int* in_sizes, int n_in,
                              void* d_out, int out_size, void* d_ws, size_t ws_size,
                              hipStream_t stream) {
  const float* q  = (const float*)d_in[0];
  const float* k  = (const float*)d_in[1];
  const float* v  = (const float*)d_in[2];
  const int*   km = (const int*)d_in[3];
  const int*   qm = (const int*)d_in[4];
  float* out  = (float*)d_out;
  float* attn = out + (size_t)BATCH * LQ * DH;
  dim3 grid(BATCH * (LQ / TQ));
  dim3 block(256);
  hipLaunchKernelGGL(sdpa_kernel, grid, block, 0, stream,
                     q, k, v, km, qm, out, attn);
}